// Round 11
// baseline (14988.031 us; speedup 1.0000x reference)
//
#include <hip/hip_runtime.h>

#define KNBR 32
#define NCELL 4096        // 16^3 Morton cells
#define MAXCHUNK 320      // ceil(20000/64)=313 <= 320
#define FCAP (MAXCHUNK * 64)
#define FT 512            // fps threads: 8 waves
#define NWAVE (FT / 64)

typedef unsigned long long u64;
typedef unsigned int u32;

// Reference-matching squared distance: ((dx*dx + dy*dy) + dz*dz), no FMA contraction.
__device__ __forceinline__ float sq_dist_nofma(float px, float py, float pz,
                                               float cx, float cy, float cz) {
    float dx = __fsub_rn(px, cx);
    float dy = __fsub_rn(py, cy);
    float dz = __fsub_rn(pz, cz);
    return __fadd_rn(__fadd_rn(__fmul_rn(dx, dx), __fmul_rn(dy, dy)), __fmul_rn(dz, dz));
}

__device__ __forceinline__ unsigned spread4(unsigned v) {
    return (v & 1u) | ((v & 2u) << 2) | ((v & 4u) << 4) | ((v & 8u) << 6);
}

// key = md_bits<<24 | (0x7FFF-orig)<<9 | chunk  (orig<32768, chunk<512).
// u64 max == (max md, then min orig); chunk id rides along. Sentinels -> key 0.
__device__ __forceinline__ u64 pack_key(float md, int orig, int c) {
    return (orig != 0x7fffffff)
        ? (((u64)__float_as_uint(md) << 24) | ((u64)(0x7FFFu - (u32)orig) << 9) | (u64)c)
        : 0ull;
}

// K1: AoS -> SoA + norms + Morton cell id + within-cell rank (counting-sort pass 1)
__global__ void prep_kernel(const float* __restrict__ coord, int N,
                            float* __restrict__ sx, float* __restrict__ sy,
                            float* __restrict__ sz, float* __restrict__ sn,
                            int* __restrict__ cell, int* __restrict__ rank,
                            int* __restrict__ hist) {
    int i = blockIdx.x * blockDim.x + threadIdx.x;
    if (i < N) {
        float x = coord[3 * i + 0];
        float y = coord[3 * i + 1];
        float z = coord[3 * i + 2];
        sx[i] = x; sy[i] = y; sz[i] = z;
        sn[i] = __fadd_rn(__fadd_rn(__fmul_rn(x, x), __fmul_rn(y, y)), __fmul_rn(z, z));
        int ix = (int)(x * 16.0f); ix = ix < 0 ? 0 : (ix > 15 ? 15 : ix);
        int iy = (int)(y * 16.0f); iy = iy < 0 ? 0 : (iy > 15 ? 15 : iy);
        int iz = (int)(z * 16.0f); iz = iz < 0 ? 0 : (iz > 15 ? 15 : iz);
        unsigned mc = spread4(ix) | (spread4(iy) << 1) | (spread4(iz) << 2);
        cell[i] = (int)mc;
        rank[i] = atomicAdd(&hist[mc], 1);
    }
}

// K2: exclusive scan of 4096-bin histogram
__global__ __launch_bounds__(1024) void scan_kernel(const int* __restrict__ hist,
                                                    int* __restrict__ cellstart) {
    __shared__ int buf[1024];
    int t = threadIdx.x;
    int h0 = hist[4 * t], h1 = hist[4 * t + 1], h2 = hist[4 * t + 2], h3 = hist[4 * t + 3];
    int s = h0 + h1 + h2 + h3;
    buf[t] = s;
    __syncthreads();
    for (int off = 1; off < 1024; off <<= 1) {
        int v = (t >= off) ? buf[t - off] : 0;
        __syncthreads();
        buf[t] += v;
        __syncthreads();
    }
    int ex = buf[t] - s;
    cellstart[4 * t]     = ex;
    cellstart[4 * t + 1] = ex + h0;
    cellstart[4 * t + 2] = ex + h0 + h1;
    cellstart[4 * t + 3] = ex + h0 + h1 + h2;
}

// K3: scatter into Morton order, packed as (x, y, z, orig_idx_bits)
__global__ void scatter_kernel(const float* __restrict__ sx, const float* __restrict__ sy,
                               const float* __restrict__ sz,
                               const int* __restrict__ cell, const int* __restrict__ rank,
                               const int* __restrict__ cellstart, int N,
                               float4* __restrict__ pts) {
    int i = blockIdx.x * blockDim.x + threadIdx.x;
    if (i < N) {
        int pos = cellstart[cell[i]] + rank[i];
        pts[pos] = make_float4(sx[i], sy[i], sz[i], __int_as_float(i));
    }
}

// K3b: sentinel padding
__global__ void pad_kernel(float4* __restrict__ pts, int N, int cap) {
    int i = N + blockIdx.x * blockDim.x + threadIdx.x;
    if (i < cap) pts[i] = make_float4(1e18f, 1e18f, 1e18f, __int_as_float(0x7fffffff));
}

// K3c: per-chunk init — md vs original point 0, chunk sphere, chunk key, winner coords.
__global__ void init_chunk_kernel(const float4* __restrict__ pts,
                                  const float* __restrict__ coord,
                                  float* __restrict__ mdbuf,
                                  float4* __restrict__ spheres,
                                  u64* __restrict__ ckeys,
                                  float4* __restrict__ wxyz_g) {
    int c = blockIdx.x, lane = threadIdx.x;
    int pos = (c << 6) + lane;
    float4 P = pts[pos];
    int orig = __float_as_int(P.w);
    bool real = (orig != 0x7fffffff);
    float c0x = coord[0], c0y = coord[1], c0z = coord[2];
    float d = sq_dist_nofma(P.x, P.y, P.z, c0x, c0y, c0z);
    float m = real ? d : -3e38f;
    mdbuf[pos] = m;
    u64 kself = pack_key(m, orig, c);
    u64 key = kself;
    float mnx = real ? P.x : 1e30f, mxx = real ? P.x : -1e30f;
    float mny = real ? P.y : 1e30f, mxy = real ? P.y : -1e30f;
    float mnz = real ? P.z : 1e30f, mxz = real ? P.z : -1e30f;
    #pragma unroll
    for (int off = 32; off; off >>= 1) {
        u64 k2 = __shfl_xor(key, off, 64);
        if (k2 > key) key = k2;
        mnx = fminf(mnx, __shfl_xor(mnx, off, 64));
        mxx = fmaxf(mxx, __shfl_xor(mxx, off, 64));
        mny = fminf(mny, __shfl_xor(mny, off, 64));
        mxy = fmaxf(mxy, __shfl_xor(mxy, off, 64));
        mnz = fminf(mnz, __shfl_xor(mnz, off, 64));
        mxz = fmaxf(mxz, __shfl_xor(mxz, off, 64));
    }
    if (kself == key) wxyz_g[c] = make_float4(P.x, P.y, P.z, 0.f);  // unique owner lane
    if (lane == 0) {
        float cx = 0.5f * (mnx + mxx), cy = 0.5f * (mny + mxy), cz = 0.5f * (mnz + mxz);
        float ex = (mxx - mnx) * 0.5f, ey = (mxy - mny) * 0.5f, ez = (mxz - mnz) * 0.5f;
        float r = sqrtf(ex * ex + ey * ey + ez * ez) * 1.0001f + 1e-7f;
        spheres[c] = make_float4(cx, cy, cz, r);
        ckeys[c] = key;
    }
}

// K4: chunked FPS, round-11: chunk keys + winner coords live in REGISTERS.
// Permuted ownership (thread wv*64+lane owns chunk c=lane*8+wv) means the wave
// that processes chunk c (wave c&7) contains c's owner lane (c>>3): phase C
// delivers updated key/coords to the owner via shuffles. LDS is only the 8-entry
// cross-wave handoff (wwin/wcoord). 2 barriers/step, zero atomics, zero key
// bank conflicts, balanced. Phase C software-pipelines the next chunk's loads.
__global__ __launch_bounds__(FT)
void fps_kernel(const float4* __restrict__ pts, float* __restrict__ mdbuf,
                const float4* __restrict__ spheres_g, const u64* __restrict__ ckeys_g,
                const float4* __restrict__ wxyz_g,
                int nchunk, int n_dst, int* __restrict__ out_idx) {
    __shared__ u64    wwin[NWAVE];
    __shared__ float4 wcoord[NWAVE];

    const int tid = threadIdx.x, lane = tid & 63, wv = tid >> 6;
    const int myc = (lane << 3) + wv;      // permuted ownership: chunk -> wave = c & 7

    // per-thread chunk state, all registers
    u64 k0 = 0ull;                          // own chunk's key (maxmd | orig | chunk)
    float wx = 0.f, wy = 0.f, wz = 0.f;     // own chunk's winner coords
    float4 S = make_float4(1e18f, 1e18f, 1e18f, 0.f);   // own chunk's sphere
    if (myc < nchunk) {
        k0 = ckeys_g[myc];
        float4 W = wxyz_g[myc];
        wx = W.x; wy = W.y; wz = W.z;
        S = spheres_g[myc];
    }
    if (tid < NWAVE) wwin[tid] = 0ull;
    if (tid == 0) out_idx[0] = 0;
    __syncthreads();

    for (int s = 1; s < n_dst; ++s) {
        // A: block argmax over register keys (no LDS on this path)
        u64 k = k0;
        #pragma unroll
        for (int off = 32; off; off >>= 1) {
            u64 k2 = __shfl_xor(k, off, 64);
            if (k2 > k) k = k2;
        }
        if (k0 == k && k0 != 0ull) {        // unique owner (keys embed chunk id)
            wwin[wv]   = k;
            wcoord[wv] = make_float4(wx, wy, wz, 0.f);
        }
        __syncthreads();                    // barrier 1
        u64 kb = wwin[0]; int wb = 0;
        #pragma unroll
        for (int w = 1; w < NWAVE; ++w) { u64 t2 = wwin[w]; if (t2 > kb) { kb = t2; wb = w; } }
        float4 C4 = wcoord[wb];
        float ncx = C4.x, ncy = C4.y, ncz = C4.z;
        if (tid == 0) out_idx[s] = (int)(0x7FFFu - (u32)((kb >> 9) & 0x7FFFull));

        // B: prune own chunk (registers only).
        // Pruned: for all p in chunk, d(p,nc) >= D - r > sqrt(maxmd) => no md change.
        // Winner's chunk never pruned (nc inside its own sphere).
        bool act = false;
        if (k0 != 0ull) {
            float maxmd = __uint_as_float((u32)(k0 >> 24));
            float Dx = ncx - S.x, Dy = ncy - S.y, Dz = ncz - S.z;
            float D2 = Dx * Dx + Dy * Dy + Dz * Dz;
            float t0 = sqrtf(maxmd) * 1.0001f + S.w;
            float thr = t0 * t0 * 1.0002f + 1e-12f;
            act = (D2 <= thr);
        }
        u64 m = __ballot(act);

        // C: this wave processes its active chunks (bit b -> chunk (b<<3)+wv),
        // 1-deep software pipeline on the global loads.
        if (m) {
            int b = __ffsll(m) - 1;
            m &= m - 1;
            int pos = ((((b << 3) + wv)) << 6) + lane;
            float4 P = pts[pos];
            float md = mdbuf[pos];
            while (true) {
                int bn = -1; float4 Pn; float mdn;
                if (m) {                     // prefetch next chunk
                    bn = __ffsll(m) - 1;
                    m &= m - 1;
                    int posn = ((((bn << 3) + wv)) << 6) + lane;
                    Pn = pts[posn];
                    mdn = mdbuf[posn];
                }
                // process current chunk b
                int c = (b << 3) + wv;
                float d = sq_dist_nofma(P.x, P.y, P.z, ncx, ncy, ncz);
                float md2 = fminf(md, d);
                mdbuf[(c << 6) + lane] = md2;
                u64 kk = pack_key(md2, __float_as_int(P.w), c);
                u64 kr = kk;
                #pragma unroll
                for (int off = 32; off; off >>= 1) {
                    u64 k2 = __shfl_xor(kr, off, 64);
                    if (k2 > kr) kr = k2;
                }
                int wl = __ffsll(__ballot(kk == kr)) - 1;   // winner lane (unique)
                float bx2 = __shfl(P.x, wl, 64);
                float by2 = __shfl(P.y, wl, 64);
                float bz2 = __shfl(P.z, wl, 64);
                if (lane == (c >> 3)) {      // deliver to owner lane (same wave)
                    k0 = kr; wx = bx2; wy = by2; wz = bz2;
                }
                if (bn < 0) break;
                b = bn; P = Pn; md = mdn;
            }
        }
        __syncthreads();                    // barrier 2
    }
}

// K5: ball query, one wave per dst. First K in-radius src indices in ascending order.
__global__ void ball_kernel(const float* __restrict__ sx, const float* __restrict__ sy,
                            const float* __restrict__ sz, const float* __restrict__ sn,
                            const int* __restrict__ idx,
                            const float* __restrict__ coord, const int* __restrict__ batch,
                            int N, int n_dst,
                            float* __restrict__ out_coord, float* __restrict__ out_esrc,
                            float* __restrict__ out_edst, float* __restrict__ out_deg,
                            float* __restrict__ out_batch,
                            int* __restrict__ nbr_i, int* __restrict__ deg_i) {
    const int d    = blockIdx.x;
    const int lane = threadIdx.x;   // block of 64
    __shared__ int nbr[KNBR];

    const int id = idx[d];
    const float cx = sx[id], cy = sy[id], cz = sz[id];
    const float dn = sn[id];
    const float RR = (float)(0.08 * 0.08);

    int cnt = 0;
    for (int base = 0; base < N && cnt < KNBR; base += 64) {
        int i = base + lane;
        bool in = false;
        if (i < N) {
            float t     = __fmul_rn(sx[i], cx);
            float inner = __fmaf_rn(sy[i], cy, t);
            inner       = __fmaf_rn(sz[i], cz, inner);
            float d2    = __fsub_rn(__fadd_rn(dn, sn[i]), __fmul_rn(2.0f, inner));
            in = (d2 <= RR);
        }
        unsigned long long m = __ballot(in);
        int pos = cnt + __popcll(m & ((1ull << lane) - 1ull));
        if (in && pos < KNBR) nbr[pos] = i;
        cnt += (int)__popcll(m);
    }
    __syncthreads();

    int deg = cnt < KNBR ? cnt : KNBR;
    if (lane < KNBR) {
        int e = (lane < deg) ? nbr[lane] : -1;
        out_esrc[d * KNBR + lane] = (float)e;
        out_edst[d * KNBR + lane] = (float)((lane < deg) ? d : -1);
        nbr_i[d * KNBR + lane] = e;
    }
    if (lane == 0) { out_deg[d] = (float)deg; deg_i[d] = deg; }
    if (lane < 3)  out_coord[d * 3 + lane] = coord[id * 3 + lane];
    if (lane == 3) out_batch[d] = (float)batch[id];
}

// K6: scatter-mean of gathered features. One block per dst, one thread per feature dim.
__global__ void agg_kernel(const float* __restrict__ feat,
                           const int* __restrict__ nbr_i, const int* __restrict__ deg_i,
                           int F, float* __restrict__ out_feat) {
    const int d = blockIdx.x;
    const int t = threadIdx.x;  // F threads
    const int deg = deg_i[d];
    float acc = 0.0f;
    for (int k = 0; k < deg; ++k) {
        int nb = nbr_i[d * KNBR + k];
        acc = __fadd_rn(acc, feat[nb * F + t]);
    }
    float den = (float)(deg > 0 ? deg : 1);
    out_feat[d * F + t] = acc / den;
}

extern "C" void kernel_launch(void* const* d_in, const int* in_sizes, int n_in,
                              void* d_out, int out_size, void* d_ws, size_t ws_size,
                              hipStream_t stream) {
    const float* coord = (const float*)d_in[0];
    const float* feat  = (const float*)d_in[1];
    const int*   batch = (const int*)d_in[2];

    const int N      = in_sizes[0] / 3;
    const int F      = in_sizes[1] / N;
    const int n_dst  = N / 4;                 // RATIO = 0.25
    const int nchunk = (N + 63) / 64;         // 313

    // workspace layout (pts 16B-aligned: 4N floats precede it; N=20000 -> 320000 B)
    float*  sx      = (float*)d_ws;
    float*  sy      = sx + N;
    float*  sz      = sy + N;
    float*  sn      = sz + N;
    float4* pts     = (float4*)(sn + N);      // FCAP packed points
    float4* spheres = pts + FCAP;             // MAXCHUNK
    float4* wxyz_g  = spheres + MAXCHUNK;     // MAXCHUNK winner coords
    float*  mdbuf   = (float*)(wxyz_g + MAXCHUNK);    // FCAP floats
    u64*    ckeys   = (u64*)(mdbuf + FCAP);   // MAXCHUNK (8B-aligned)
    int*    cell      = (int*)(ckeys + MAXCHUNK);
    int*    rank      = cell + N;
    int*    hist      = rank + N;
    int*    cellstart = hist + NCELL;
    int*    idx       = cellstart + NCELL;
    int*    nbr_i     = idx + n_dst;
    int*    deg_i     = nbr_i + n_dst * KNBR;

    // output layout (all float32), reference return order
    float* out     = (float*)d_out;
    float* o_coord = out;                         // n_dst*3
    float* o_feat  = o_coord + (size_t)n_dst * 3; // n_dst*F
    float* o_esrc  = o_feat  + (size_t)n_dst * F; // n_dst*K
    float* o_edst  = o_esrc  + (size_t)n_dst * KNBR;
    float* o_deg   = o_edst  + (size_t)n_dst * KNBR;
    float* o_batch = o_deg   + n_dst;

    hipMemsetAsync(hist, 0, NCELL * sizeof(int), stream);
    prep_kernel<<<(N + 255) / 256, 256, 0, stream>>>(coord, N, sx, sy, sz, sn,
                                                     cell, rank, hist);
    scan_kernel<<<1, 1024, 0, stream>>>(hist, cellstart);
    scatter_kernel<<<(N + 255) / 256, 256, 0, stream>>>(sx, sy, sz, cell, rank,
                                                        cellstart, N, pts);
    pad_kernel<<<(nchunk * 64 - N + 255) / 256, 256, 0, stream>>>(pts, N, nchunk * 64);
    init_chunk_kernel<<<nchunk, 64, 0, stream>>>(pts, coord, mdbuf, spheres, ckeys,
                                                 wxyz_g);
    fps_kernel<<<1, FT, 0, stream>>>(pts, mdbuf, spheres, ckeys, wxyz_g,
                                     nchunk, n_dst, idx);
    ball_kernel<<<n_dst, 64, 0, stream>>>(sx, sy, sz, sn, idx, coord, batch, N, n_dst,
                                          o_coord, o_esrc, o_edst, o_deg, o_batch,
                                          nbr_i, deg_i);
    agg_kernel<<<n_dst, F, 0, stream>>>(feat, nbr_i, deg_i, F, o_feat);
}

// Round 12
// 10535.798 us; speedup vs baseline: 1.4226x; 1.4226x over previous
//
#include <hip/hip_runtime.h>

#define KNBR 32
#define NCELL 4096        // 16^3 Morton cells
#define MAXCHUNK 320      // ceil(20000/64)=313 <= 320
#define FCAP (MAXCHUNK * 64)
#define FT 512            // fps threads: 8 waves
#define NWAVE (FT / 64)

typedef unsigned long long u64;
typedef unsigned int u32;

// Reference-matching squared distance: ((dx*dx + dy*dy) + dz*dz), no FMA contraction.
__device__ __forceinline__ float sq_dist_nofma(float px, float py, float pz,
                                               float cx, float cy, float cz) {
    float dx = __fsub_rn(px, cx);
    float dy = __fsub_rn(py, cy);
    float dz = __fsub_rn(pz, cz);
    return __fadd_rn(__fadd_rn(__fmul_rn(dx, dx), __fmul_rn(dy, dy)), __fmul_rn(dz, dz));
}

__device__ __forceinline__ unsigned spread4(unsigned v) {
    return (v & 1u) | ((v & 2u) << 2) | ((v & 4u) << 4) | ((v & 8u) << 6);
}

// key = md_bits<<24 | (0x7FFF-orig)<<9 | chunk  (orig<32768, chunk<512).
// u64 max == (max md, then min orig); chunk id rides along. Sentinels -> key 0.
__device__ __forceinline__ u64 pack_key(float md, int orig, int c) {
    return (orig != 0x7fffffff)
        ? (((u64)__float_as_uint(md) << 24) | ((u64)(0x7FFFu - (u32)orig) << 9) | (u64)c)
        : 0ull;
}

// DPP-shifted u64 (two 32-bit halves); out-of-pattern lanes contribute 0 (identity for max).
template<int CTRL, int RM>
__device__ __forceinline__ u64 dpp64(u64 v) {
    int lo = __builtin_amdgcn_update_dpp(0, (int)(u32)v,         CTRL, RM, 0xf, false);
    int hi = __builtin_amdgcn_update_dpp(0, (int)(u32)(v >> 32), CTRL, RM, 0xf, false);
    return ((u64)(u32)hi << 32) | (u32)lo;
}

// Canonical CDNA wave64 max-reduction: row_shr 1/2/4/8, row_bcast15(rm=0xa),
// row_bcast31(rm=0xc); lane 63 holds the max; readlane broadcasts to all.
// ~6 dependent VALU levels (~100 cyc) vs ~700 cyc for a ds_bpermute butterfly.
__device__ __forceinline__ u64 wave_max_u64(u64 v) {
    u64 t;
    t = dpp64<0x111, 0xf>(v); v = t > v ? t : v;   // row_shr:1
    t = dpp64<0x112, 0xf>(v); v = t > v ? t : v;   // row_shr:2
    t = dpp64<0x114, 0xf>(v); v = t > v ? t : v;   // row_shr:4
    t = dpp64<0x118, 0xf>(v); v = t > v ? t : v;   // row_shr:8
    t = dpp64<0x142, 0xa>(v); v = t > v ? t : v;   // row_bcast:15 -> rows 1,3
    t = dpp64<0x143, 0xc>(v); v = t > v ? t : v;   // row_bcast:31 -> rows 2,3
    u32 lo = (u32)__builtin_amdgcn_readlane((int)(u32)v, 63);
    u32 hi = (u32)__builtin_amdgcn_readlane((int)(u32)(v >> 32), 63);
    return ((u64)hi << 32) | lo;
}

// K1: AoS -> SoA + norms + Morton cell id + within-cell rank (counting-sort pass 1)
__global__ void prep_kernel(const float* __restrict__ coord, int N,
                            float* __restrict__ sx, float* __restrict__ sy,
                            float* __restrict__ sz, float* __restrict__ sn,
                            int* __restrict__ cell, int* __restrict__ rank,
                            int* __restrict__ hist) {
    int i = blockIdx.x * blockDim.x + threadIdx.x;
    if (i < N) {
        float x = coord[3 * i + 0];
        float y = coord[3 * i + 1];
        float z = coord[3 * i + 2];
        sx[i] = x; sy[i] = y; sz[i] = z;
        sn[i] = __fadd_rn(__fadd_rn(__fmul_rn(x, x), __fmul_rn(y, y)), __fmul_rn(z, z));
        int ix = (int)(x * 16.0f); ix = ix < 0 ? 0 : (ix > 15 ? 15 : ix);
        int iy = (int)(y * 16.0f); iy = iy < 0 ? 0 : (iy > 15 ? 15 : iy);
        int iz = (int)(z * 16.0f); iz = iz < 0 ? 0 : (iz > 15 ? 15 : iz);
        unsigned mc = spread4(ix) | (spread4(iy) << 1) | (spread4(iz) << 2);
        cell[i] = (int)mc;
        rank[i] = atomicAdd(&hist[mc], 1);
    }
}

// K2: exclusive scan of 4096-bin histogram
__global__ __launch_bounds__(1024) void scan_kernel(const int* __restrict__ hist,
                                                    int* __restrict__ cellstart) {
    __shared__ int buf[1024];
    int t = threadIdx.x;
    int h0 = hist[4 * t], h1 = hist[4 * t + 1], h2 = hist[4 * t + 2], h3 = hist[4 * t + 3];
    int s = h0 + h1 + h2 + h3;
    buf[t] = s;
    __syncthreads();
    for (int off = 1; off < 1024; off <<= 1) {
        int v = (t >= off) ? buf[t - off] : 0;
        __syncthreads();
        buf[t] += v;
        __syncthreads();
    }
    int ex = buf[t] - s;
    cellstart[4 * t]     = ex;
    cellstart[4 * t + 1] = ex + h0;
    cellstart[4 * t + 2] = ex + h0 + h1;
    cellstart[4 * t + 3] = ex + h0 + h1 + h2;
}

// K3: scatter into Morton order, packed as (x, y, z, orig_idx_bits)
__global__ void scatter_kernel(const float* __restrict__ sx, const float* __restrict__ sy,
                               const float* __restrict__ sz,
                               const int* __restrict__ cell, const int* __restrict__ rank,
                               const int* __restrict__ cellstart, int N,
                               float4* __restrict__ pts) {
    int i = blockIdx.x * blockDim.x + threadIdx.x;
    if (i < N) {
        int pos = cellstart[cell[i]] + rank[i];
        pts[pos] = make_float4(sx[i], sy[i], sz[i], __int_as_float(i));
    }
}

// K3b: sentinel padding
__global__ void pad_kernel(float4* __restrict__ pts, int N, int cap) {
    int i = N + blockIdx.x * blockDim.x + threadIdx.x;
    if (i < cap) pts[i] = make_float4(1e18f, 1e18f, 1e18f, __int_as_float(0x7fffffff));
}

// K3c: per-chunk init — md vs original point 0, chunk sphere, chunk key, winner coords.
__global__ void init_chunk_kernel(const float4* __restrict__ pts,
                                  const float* __restrict__ coord,
                                  float* __restrict__ mdbuf,
                                  float4* __restrict__ spheres,
                                  u64* __restrict__ ckeys,
                                  float4* __restrict__ wxyz_g) {
    int c = blockIdx.x, lane = threadIdx.x;
    int pos = (c << 6) + lane;
    float4 P = pts[pos];
    int orig = __float_as_int(P.w);
    bool real = (orig != 0x7fffffff);
    float c0x = coord[0], c0y = coord[1], c0z = coord[2];
    float d = sq_dist_nofma(P.x, P.y, P.z, c0x, c0y, c0z);
    float m = real ? d : -3e38f;
    mdbuf[pos] = m;
    u64 kself = pack_key(m, orig, c);
    u64 key = kself;
    float mnx = real ? P.x : 1e30f, mxx = real ? P.x : -1e30f;
    float mny = real ? P.y : 1e30f, mxy = real ? P.y : -1e30f;
    float mnz = real ? P.z : 1e30f, mxz = real ? P.z : -1e30f;
    #pragma unroll
    for (int off = 32; off; off >>= 1) {
        u64 k2 = __shfl_xor(key, off, 64);
        if (k2 > key) key = k2;
        mnx = fminf(mnx, __shfl_xor(mnx, off, 64));
        mxx = fmaxf(mxx, __shfl_xor(mxx, off, 64));
        mny = fminf(mny, __shfl_xor(mny, off, 64));
        mxy = fmaxf(mxy, __shfl_xor(mxy, off, 64));
        mnz = fminf(mnz, __shfl_xor(mnz, off, 64));
        mxz = fmaxf(mxz, __shfl_xor(mxz, off, 64));
    }
    if (kself == key) wxyz_g[c] = make_float4(P.x, P.y, P.z, 0.f);  // unique owner lane
    if (lane == 0) {
        float cx = 0.5f * (mnx + mxx), cy = 0.5f * (mny + mxy), cz = 0.5f * (mnz + mxz);
        float ex = (mxx - mnx) * 0.5f, ey = (mxy - mny) * 0.5f, ez = (mxz - mnz) * 0.5f;
        float r = sqrtf(ex * ex + ey * ey + ez * ez) * 1.0001f + 1e-7f;
        spheres[c] = make_float4(cx, cy, cz, r);
        ckeys[c] = key;
    }
}

// K4: chunked FPS, round-12: DPP wave-max (VALU, ~100cyc) replaces ds_bpermute
// butterflies (~700cyc); single barrier per step via parity-double-buffered
// wwin/wcoord. Permuted ownership (thread wv*64+lane owns chunk c=lane*8+wv):
// chunk c is pruned/processed/key-delivered entirely inside wave c&7, so keys,
// winner coords, and mdbuf have NO cross-wave dependencies — only the 8-entry
// wwin handoff needs sync. A wave's parity-buffer write at step s+2 is separated
// from any straggler's read at step s by the barrier at s+1.
__global__ __launch_bounds__(FT)
void fps_kernel(const float4* __restrict__ pts, float* __restrict__ mdbuf,
                const float4* __restrict__ spheres_g, const u64* __restrict__ ckeys_g,
                const float4* __restrict__ wxyz_g,
                int nchunk, int n_dst, int* __restrict__ out_idx) {
    __shared__ u64    wwin[2][NWAVE];
    __shared__ float4 wcoord[2][NWAVE];

    const int tid = threadIdx.x, lane = tid & 63, wv = tid >> 6;
    const int myc = (lane << 3) + wv;      // permuted ownership: chunk -> wave = c & 7

    // per-thread chunk state, all registers
    u64 k0 = 0ull;                          // own chunk's key (maxmd | orig | chunk)
    float wx = 0.f, wy = 0.f, wz = 0.f;     // own chunk's winner coords
    float4 S = make_float4(1e18f, 1e18f, 1e18f, 0.f);   // own chunk's sphere
    if (myc < nchunk) {
        k0 = ckeys_g[myc];
        float4 W = wxyz_g[myc];
        wx = W.x; wy = W.y; wz = W.z;
        S = spheres_g[myc];
    }
    if (tid == 0) out_idx[0] = 0;
    __syncthreads();

    int par = 1;
    for (int s = 1; s < n_dst; ++s) {
        // A: wave argmax over register keys via DPP; owner writes parity slot.
        u64 k = wave_max_u64(k0);
        if (k0 == k && k0 != 0ull) {        // unique owner (keys embed chunk id)
            wwin[par][wv]   = k;
            wcoord[par][wv] = make_float4(wx, wy, wz, 0.f);
        }
        __syncthreads();                    // the ONLY barrier per step
        u64 kb = wwin[par][0]; int wb = 0;
        #pragma unroll
        for (int w = 1; w < NWAVE; ++w) {
            u64 t2 = wwin[par][w];
            if (t2 > kb) { kb = t2; wb = w; }
        }
        float4 C4 = wcoord[par][wb];
        float ncx = C4.x, ncy = C4.y, ncz = C4.z;
        if (tid == 0) out_idx[s] = (int)(0x7FFFu - (u32)((kb >> 9) & 0x7FFFull));
        par ^= 1;

        // B: prune own chunk (registers only).
        // Pruned: for all p in chunk, d(p,nc) >= D - r > sqrt(maxmd) => no md change.
        // Winner's chunk never pruned (nc inside its own sphere).
        bool act = false;
        if (k0 != 0ull) {
            float maxmd = __uint_as_float((u32)(k0 >> 24));
            float Dx = ncx - S.x, Dy = ncy - S.y, Dz = ncz - S.z;
            float D2 = Dx * Dx + Dy * Dy + Dz * Dz;
            float t0 = sqrtf(maxmd) * 1.0001f + S.w;
            float thr = t0 * t0 * 1.0002f + 1e-12f;
            act = (D2 <= thr);
        }
        u64 m = __ballot(act);

        // C: this wave processes its active chunks (bit b -> chunk (b<<3)+wv),
        // 1-deep software pipeline on the global loads; DPP key rebuild.
        if (m) {
            int b = __ffsll(m) - 1;
            m &= m - 1;
            int pos = ((((b << 3) + wv)) << 6) + lane;
            float4 P = pts[pos];
            float md = mdbuf[pos];
            while (true) {
                int bn = -1; float4 Pn; float mdn;
                if (m) {                     // prefetch next chunk
                    bn = __ffsll(m) - 1;
                    m &= m - 1;
                    int posn = ((((bn << 3) + wv)) << 6) + lane;
                    Pn = pts[posn];
                    mdn = mdbuf[posn];
                }
                // process current chunk b
                int c = (b << 3) + wv;
                float d = sq_dist_nofma(P.x, P.y, P.z, ncx, ncy, ncz);
                float md2 = fminf(md, d);
                mdbuf[(c << 6) + lane] = md2;
                u64 kk = pack_key(md2, __float_as_int(P.w), c);
                u64 kr = wave_max_u64(kk);
                int wl = __ffsll(__ballot(kk == kr)) - 1;   // winner lane (unique)
                float bx2 = __shfl(P.x, wl, 64);
                float by2 = __shfl(P.y, wl, 64);
                float bz2 = __shfl(P.z, wl, 64);
                if (lane == (c >> 3)) {      // deliver to owner lane (same wave)
                    k0 = kr; wx = bx2; wy = by2; wz = bz2;
                }
                if (bn < 0) break;
                b = bn; P = Pn; md = mdn;
            }
        }
    }
}

// K5: ball query, one wave per dst. First K in-radius src indices in ascending order.
__global__ void ball_kernel(const float* __restrict__ sx, const float* __restrict__ sy,
                            const float* __restrict__ sz, const float* __restrict__ sn,
                            const int* __restrict__ idx,
                            const float* __restrict__ coord, const int* __restrict__ batch,
                            int N, int n_dst,
                            float* __restrict__ out_coord, float* __restrict__ out_esrc,
                            float* __restrict__ out_edst, float* __restrict__ out_deg,
                            float* __restrict__ out_batch,
                            int* __restrict__ nbr_i, int* __restrict__ deg_i) {
    const int d    = blockIdx.x;
    const int lane = threadIdx.x;   // block of 64
    __shared__ int nbr[KNBR];

    const int id = idx[d];
    const float cx = sx[id], cy = sy[id], cz = sz[id];
    const float dn = sn[id];
    const float RR = (float)(0.08 * 0.08);

    int cnt = 0;
    for (int base = 0; base < N && cnt < KNBR; base += 64) {
        int i = base + lane;
        bool in = false;
        if (i < N) {
            float t     = __fmul_rn(sx[i], cx);
            float inner = __fmaf_rn(sy[i], cy, t);
            inner       = __fmaf_rn(sz[i], cz, inner);
            float d2    = __fsub_rn(__fadd_rn(dn, sn[i]), __fmul_rn(2.0f, inner));
            in = (d2 <= RR);
        }
        unsigned long long m = __ballot(in);
        int pos = cnt + __popcll(m & ((1ull << lane) - 1ull));
        if (in && pos < KNBR) nbr[pos] = i;
        cnt += (int)__popcll(m);
    }
    __syncthreads();

    int deg = cnt < KNBR ? cnt : KNBR;
    if (lane < KNBR) {
        int e = (lane < deg) ? nbr[lane] : -1;
        out_esrc[d * KNBR + lane] = (float)e;
        out_edst[d * KNBR + lane] = (float)((lane < deg) ? d : -1);
        nbr_i[d * KNBR + lane] = e;
    }
    if (lane == 0) { out_deg[d] = (float)deg; deg_i[d] = deg; }
    if (lane < 3)  out_coord[d * 3 + lane] = coord[id * 3 + lane];
    if (lane == 3) out_batch[d] = (float)batch[id];
}

// K6: scatter-mean of gathered features. One block per dst, one thread per feature dim.
__global__ void agg_kernel(const float* __restrict__ feat,
                           const int* __restrict__ nbr_i, const int* __restrict__ deg_i,
                           int F, float* __restrict__ out_feat) {
    const int d = blockIdx.x;
    const int t = threadIdx.x;  // F threads
    const int deg = deg_i[d];
    float acc = 0.0f;
    for (int k = 0; k < deg; ++k) {
        int nb = nbr_i[d * KNBR + k];
        acc = __fadd_rn(acc, feat[nb * F + t]);
    }
    float den = (float)(deg > 0 ? deg : 1);
    out_feat[d * F + t] = acc / den;
}

extern "C" void kernel_launch(void* const* d_in, const int* in_sizes, int n_in,
                              void* d_out, int out_size, void* d_ws, size_t ws_size,
                              hipStream_t stream) {
    const float* coord = (const float*)d_in[0];
    const float* feat  = (const float*)d_in[1];
    const int*   batch = (const int*)d_in[2];

    const int N      = in_sizes[0] / 3;
    const int F      = in_sizes[1] / N;
    const int n_dst  = N / 4;                 // RATIO = 0.25
    const int nchunk = (N + 63) / 64;         // 313

    // workspace layout (pts 16B-aligned: 4N floats precede it; N=20000 -> 320000 B)
    float*  sx      = (float*)d_ws;
    float*  sy      = sx + N;
    float*  sz      = sy + N;
    float*  sn      = sz + N;
    float4* pts     = (float4*)(sn + N);      // FCAP packed points
    float4* spheres = pts + FCAP;             // MAXCHUNK
    float4* wxyz_g  = spheres + MAXCHUNK;     // MAXCHUNK winner coords
    float*  mdbuf   = (float*)(wxyz_g + MAXCHUNK);    // FCAP floats
    u64*    ckeys   = (u64*)(mdbuf + FCAP);   // MAXCHUNK (8B-aligned)
    int*    cell      = (int*)(ckeys + MAXCHUNK);
    int*    rank      = cell + N;
    int*    hist      = rank + N;
    int*    cellstart = hist + NCELL;
    int*    idx       = cellstart + NCELL;
    int*    nbr_i     = idx + n_dst;
    int*    deg_i     = nbr_i + n_dst * KNBR;

    // output layout (all float32), reference return order
    float* out     = (float*)d_out;
    float* o_coord = out;                         // n_dst*3
    float* o_feat  = o_coord + (size_t)n_dst * 3; // n_dst*F
    float* o_esrc  = o_feat  + (size_t)n_dst * F; // n_dst*K
    float* o_edst  = o_esrc  + (size_t)n_dst * KNBR;
    float* o_deg   = o_edst  + (size_t)n_dst * KNBR;
    float* o_batch = o_deg   + n_dst;

    hipMemsetAsync(hist, 0, NCELL * sizeof(int), stream);
    prep_kernel<<<(N + 255) / 256, 256, 0, stream>>>(coord, N, sx, sy, sz, sn,
                                                     cell, rank, hist);
    scan_kernel<<<1, 1024, 0, stream>>>(hist, cellstart);
    scatter_kernel<<<(N + 255) / 256, 256, 0, stream>>>(sx, sy, sz, cell, rank,
                                                        cellstart, N, pts);
    pad_kernel<<<(nchunk * 64 - N + 255) / 256, 256, 0, stream>>>(pts, N, nchunk * 64);
    init_chunk_kernel<<<nchunk, 64, 0, stream>>>(pts, coord, mdbuf, spheres, ckeys,
                                                 wxyz_g);
    fps_kernel<<<1, FT, 0, stream>>>(pts, mdbuf, spheres, ckeys, wxyz_g,
                                     nchunk, n_dst, idx);
    ball_kernel<<<n_dst, 64, 0, stream>>>(sx, sy, sz, sn, idx, coord, batch, N, n_dst,
                                          o_coord, o_esrc, o_edst, o_deg, o_batch,
                                          nbr_i, deg_i);
    agg_kernel<<<n_dst, F, 0, stream>>>(feat, nbr_i, deg_i, F, o_feat);
}